// Round 1
// baseline (276.055 us; speedup 1.0000x reference)
//
#include <hip/hip_runtime.h>
#include <math.h>

typedef __bf16 bf16;
typedef __bf16 bf16x8 __attribute__((ext_vector_type(8)));
typedef __bf16 bf16x4 __attribute__((ext_vector_type(4)));
typedef float  f32x4  __attribute__((ext_vector_type(4)));

#define B_DIM 2
#define T_LEN 2048
#define D_DIM 1024
#define N_HEAD 16
#define HEAD_D 64
#define M_ROWS (B_DIM * T_LEN)  // 4096

// ---------------- f32 -> bf16 conversion (vectorized x4) ----------------
__global__ void cvt_f32_bf16(const float* __restrict__ src, bf16* __restrict__ dst, int n4) {
    int id = blockIdx.x * blockDim.x + threadIdx.x;
    if (id >= n4) return;
    float4 v = reinterpret_cast<const float4*>(src)[id];
    bf16x4 w;
    w[0] = (bf16)v.x; w[1] = (bf16)v.y; w[2] = (bf16)v.z; w[3] = (bf16)v.w;
    reinterpret_cast<bf16x4*>(dst)[id] = w;
}

// ---------------- GEMM: C[M,N] = A[M,K] * Bm[N,K]^T (bf16 in, f32 acc) ----
// MODE 0: write bf16 head-major [B,H,T,hd]   (for q,k,v)
// MODE 1: write f32 row-major [M,N]          (final output)
template <int MODE>
__global__ __launch_bounds__(256)
void gemm_bt(const bf16* __restrict__ A, const bf16* __restrict__ Bm, void* __restrict__ Cout) {
    constexpr int K = D_DIM;
    __shared__ bf16 As[128][72];   // pad: row stride 144B (16B-aligned)
    __shared__ bf16 Bs[128][72];
    const int tid  = threadIdx.x;
    const int lane = tid & 63, wave = tid >> 6;
    const int wr = wave >> 1, wc = wave & 1;     // 2x2 waves of 64x64
    const int m0 = blockIdx.y * 128, n0 = blockIdx.x * 128;
    const int rowg = lane >> 4, col0 = lane & 15;

    f32x4 acc[4][4];
    f32x4 zero = {0.f, 0.f, 0.f, 0.f};
#pragma unroll
    for (int i = 0; i < 4; i++)
#pragma unroll
        for (int j = 0; j < 4; j++) acc[i][j] = zero;

    for (int k0 = 0; k0 < K; k0 += 64) {
        // stage A,B tiles: 128 rows x 64 cols bf16 = 128B/row, 8x16B chunks/row
#pragma unroll
        for (int cc = 0; cc < 4; ++cc) {
            int c = tid + cc * 256;            // 0..1023
            int row = c >> 3, cg = c & 7;
            *reinterpret_cast<uint4*>(&As[row][cg * 8]) =
                *reinterpret_cast<const uint4*>(A + (size_t)(m0 + row) * K + k0 + cg * 8);
            *reinterpret_cast<uint4*>(&Bs[row][cg * 8]) =
                *reinterpret_cast<const uint4*>(Bm + (size_t)(n0 + row) * K + k0 + cg * 8);
        }
        __syncthreads();
#pragma unroll
        for (int kk = 0; kk < 2; ++kk) {
            const int kc = kk * 32 + rowg * 8;
            bf16x8 af[4], bfr[4];
#pragma unroll
            for (int i = 0; i < 4; i++)
                af[i] = *reinterpret_cast<const bf16x8*>(&As[wr * 64 + i * 16 + col0][kc]);
#pragma unroll
            for (int j = 0; j < 4; j++)
                bfr[j] = *reinterpret_cast<const bf16x8*>(&Bs[wc * 64 + j * 16 + col0][kc]);
#pragma unroll
            for (int i = 0; i < 4; i++)
#pragma unroll
                for (int j = 0; j < 4; j++)
                    acc[i][j] = __builtin_amdgcn_mfma_f32_16x16x32_bf16(af[i], bfr[j], acc[i][j], 0, 0, 0);
        }
        __syncthreads();
    }

    // epilogue: C/D layout col=lane&15, row=(lane>>4)*4+r
#pragma unroll
    for (int i = 0; i < 4; i++)
#pragma unroll
        for (int j = 0; j < 4; j++)
#pragma unroll
            for (int r = 0; r < 4; r++) {
                float v = acc[i][j][r];
                int m = m0 + wr * 64 + i * 16 + rowg * 4 + r;
                int n = n0 + wc * 64 + j * 16 + col0;
                if constexpr (MODE == 0) {
                    int b = m >> 11, t = m & 2047, h = n >> 6, d = n & 63;
                    reinterpret_cast<bf16*>(Cout)[(((size_t)(b * N_HEAD + h)) * T_LEN + t) * HEAD_D + d] = (bf16)v;
                } else {
                    reinterpret_cast<float*>(Cout)[(size_t)m * D_DIM + n] = v;
                }
            }
}

// ---------------- RoPE in place on head-major q,k; q gets 1/8 scale -------
__global__ void rope_inplace(bf16* __restrict__ q, bf16* __restrict__ k,
                             const float* __restrict__ cosT, const float* __restrict__ sinT) {
    int id = blockIdx.x * blockDim.x + threadIdx.x;   // B*H*T*32 = 2^21 threads
    int i = id & 31;
    int t = (id >> 5) & 2047;
    int bh = id >> 16;
    float c = cosT[t * 32 + i], s = sinT[t * 32 + i];
    size_t p = ((size_t)bh * T_LEN + t) * HEAD_D + 2 * i;
    float q0 = (float)q[p], q1 = (float)q[p + 1];
    q[p]     = (bf16)((q0 * c - q1 * s) * 0.125f);
    q[p + 1] = (bf16)((q0 * s + q1 * c) * 0.125f);
    float k0 = (float)k[p], k1 = (float)k[p + 1];
    k[p]     = (bf16)(k0 * c - k1 * s);
    k[p + 1] = (bf16)(k0 * s + k1 * c);
}

// ---------------- causal flash attention, QBLK=KVBLK=64, 4 waves ----------
__global__ __launch_bounds__(256)
void attn_fwd(const bf16* __restrict__ qh, const bf16* __restrict__ kh,
              const bf16* __restrict__ vh, bf16* __restrict__ ao) {
    __shared__ bf16 Ks[64][72];
    __shared__ bf16 Vt[64][72];        // transposed V: Vt[d][t]
    __shared__ bf16 Ps[4][16][72];     // per-wave P tile
    const int tid = threadIdx.x, lane = tid & 63, wave = tid >> 6;
    const int rowg = lane >> 4, col0 = lane & 15;
    const int qt = blockIdx.x, bh = blockIdx.y;
    const int q0 = qt * 64;
    const size_t base = (size_t)bh * T_LEN * HEAD_D;

    // Q fragments (already rope'd and pre-scaled by 1/8)
    bf16x8 aq[2];
#pragma unroll
    for (int kk = 0; kk < 2; kk++)
        aq[kk] = *reinterpret_cast<const bf16x8*>(
            &qh[base + (size_t)(q0 + wave * 16 + col0) * HEAD_D + kk * 32 + rowg * 8]);

    f32x4 o[4];
    f32x4 zero = {0.f, 0.f, 0.f, 0.f};
    float mi[4], li[4];
#pragma unroll
    for (int j = 0; j < 4; j++) o[j] = zero;
#pragma unroll
    for (int r = 0; r < 4; r++) { mi[r] = -__builtin_inff(); li[r] = 0.f; }

    for (int kt = 0; kt <= qt; ++kt) {
        const int kv0 = kt * 64;
        // stage K (row-major) and V (transposed)
#pragma unroll
        for (int cc = 0; cc < 2; ++cc) {
            int c = tid + cc * 256;           // 0..511
            int row = c >> 3, cg = c & 7;
            *reinterpret_cast<uint4*>(&Ks[row][cg * 8]) =
                *reinterpret_cast<const uint4*>(&kh[base + (size_t)(kv0 + row) * HEAD_D + cg * 8]);
            bf16x8 vv = *reinterpret_cast<const bf16x8*>(&vh[base + (size_t)(kv0 + row) * HEAD_D + cg * 8]);
#pragma unroll
            for (int e = 0; e < 8; e++) Vt[cg * 8 + e][row] = vv[e];
        }
        __syncthreads();

        // S = Q*K^T  (16 q-rows x 64 k-cols per wave)
        f32x4 s[4];
#pragma unroll
        for (int j = 0; j < 4; j++) s[j] = zero;
#pragma unroll
        for (int kk = 0; kk < 2; kk++) {
            const int kc = kk * 32 + rowg * 8;
#pragma unroll
            for (int j = 0; j < 4; j++) {
                bf16x8 bk = *reinterpret_cast<const bf16x8*>(&Ks[j * 16 + col0][kc]);
                s[j] = __builtin_amdgcn_mfma_f32_16x16x32_bf16(aq[kk], bk, s[j], 0, 0, 0);
            }
        }
        if (kt == qt) {   // diagonal tile: mask k > q
#pragma unroll
            for (int j = 0; j < 4; j++)
#pragma unroll
                for (int r = 0; r < 4; r++) {
                    int qrow = wave * 16 + rowg * 4 + r, kcol = j * 16 + col0;
                    if (kcol > qrow) s[j][r] = -__builtin_inff();
                }
        }
        // online softmax (row stats across the 16 lanes of each col group)
#pragma unroll
        for (int r = 0; r < 4; r++) {
            float mx = fmaxf(fmaxf(s[0][r], s[1][r]), fmaxf(s[2][r], s[3][r]));
#pragma unroll
            for (int d = 1; d < 16; d <<= 1) mx = fmaxf(mx, __shfl_xor(mx, d));
            float mnew = fmaxf(mi[r], mx);
            float alpha = __expf(mi[r] - mnew);
            float ps = 0.f;
#pragma unroll
            for (int j = 0; j < 4; j++) {
                float p = __expf(s[j][r] - mnew);
                s[j][r] = p;
                ps += p;
            }
#pragma unroll
            for (int d = 1; d < 16; d <<= 1) ps += __shfl_xor(ps, d);
            li[r] = li[r] * alpha + ps;
#pragma unroll
            for (int j = 0; j < 4; j++) o[j][r] *= alpha;
            mi[r] = mnew;
        }
        // P -> LDS (bf16) to reach MFMA A-frag layout
#pragma unroll
        for (int j = 0; j < 4; j++)
#pragma unroll
            for (int r = 0; r < 4; r++)
                Ps[wave][rowg * 4 + r][j * 16 + col0] = (bf16)s[j][r];
        __syncthreads();
        // O += P * V
#pragma unroll
        for (int kk = 0; kk < 2; kk++) {
            const int kc = kk * 32 + rowg * 8;
            bf16x8 pa = *reinterpret_cast<const bf16x8*>(&Ps[wave][col0][kc]);
#pragma unroll
            for (int j = 0; j < 4; j++) {
                bf16x8 bv = *reinterpret_cast<const bf16x8*>(&Vt[j * 16 + col0][kc]);
                o[j] = __builtin_amdgcn_mfma_f32_16x16x32_bf16(pa, bv, o[j], 0, 0, 0);
            }
        }
        __syncthreads();
    }

    // normalize and write ao as row-major [B*T, D] bf16
    const int b = bh >> 4, h = bh & 15;
#pragma unroll
    for (int r = 0; r < 4; r++) {
        float inv = 1.f / li[r];
        int t = q0 + wave * 16 + rowg * 4 + r;
#pragma unroll
        for (int j = 0; j < 4; j++) {
            int d = j * 16 + col0;
            ao[((size_t)(b * T_LEN + t)) * D_DIM + h * HEAD_D + d] = (bf16)(o[j][r] * inv);
        }
    }
}

// --------------------------------------------------------------------------
extern "C" void kernel_launch(void* const* d_in, const int* in_sizes, int n_in,
                              void* d_out, int out_size, void* d_ws, size_t ws_size,
                              hipStream_t stream) {
    const float* x  = (const float*)d_in[0];
    const float* Wq = (const float*)d_in[1];
    const float* Wk = (const float*)d_in[2];
    const float* Wv = (const float*)d_in[3];
    const float* Wo = (const float*)d_in[4];
    const float* fc = (const float*)d_in[5];
    const float* fs = (const float*)d_in[6];
    float* out = (float*)d_out;

    char* ws = (char*)d_ws;
    const size_t MB = 1024 * 1024;
    bf16* xb  = (bf16*)(ws);             // 8 MiB  [4096,1024]
    bf16* wqb = (bf16*)(ws + 8 * MB);    // 2 MiB
    bf16* wkb = (bf16*)(ws + 10 * MB);
    bf16* wvb = (bf16*)(ws + 12 * MB);
    bf16* wob = (bf16*)(ws + 14 * MB);
    bf16* qhd = (bf16*)(ws + 16 * MB);   // 8 MiB head-major [B,H,T,hd]
    bf16* khd = (bf16*)(ws + 24 * MB);
    bf16* vhd = (bf16*)(ws + 32 * MB);
    bf16* ao  = (bf16*)(ws + 40 * MB);   // 8 MiB row-major [B*T, D]
    // total 48 MiB of d_ws

    cvt_f32_bf16<<<4096, 256, 0, stream>>>(x, xb, M_ROWS * D_DIM / 4);
    cvt_f32_bf16<<<1024, 256, 0, stream>>>(Wq, wqb, D_DIM * D_DIM / 4);
    cvt_f32_bf16<<<1024, 256, 0, stream>>>(Wk, wkb, D_DIM * D_DIM / 4);
    cvt_f32_bf16<<<1024, 256, 0, stream>>>(Wv, wvb, D_DIM * D_DIM / 4);
    cvt_f32_bf16<<<1024, 256, 0, stream>>>(Wo, wob, D_DIM * D_DIM / 4);

    dim3 gg(D_DIM / 128, M_ROWS / 128);  // (8, 32)
    gemm_bt<0><<<gg, 256, 0, stream>>>(xb, wqb, qhd);
    gemm_bt<0><<<gg, 256, 0, stream>>>(xb, wkb, khd);
    gemm_bt<0><<<gg, 256, 0, stream>>>(xb, wvb, vhd);

    rope_inplace<<<(B_DIM * N_HEAD * T_LEN * 32) / 256, 256, 0, stream>>>(qhd, khd, fc, fs);

    dim3 ga(T_LEN / 64, B_DIM * N_HEAD);  // (32, 32)
    attn_fwd<<<ga, 256, 0, stream>>>(qhd, khd, vhd, ao);

    gemm_bt<1><<<gg, 256, 0, stream>>>(ao, wob, out);
}

// Round 2
// 163.616 us; speedup vs baseline: 1.6872x; 1.6872x over previous
//
#include <hip/hip_runtime.h>
#include <math.h>

typedef __bf16 bf16;
typedef __bf16 bf16x8 __attribute__((ext_vector_type(8)));
typedef __bf16 bf16x4 __attribute__((ext_vector_type(4)));
typedef __bf16 bf16x2 __attribute__((ext_vector_type(2)));
typedef float  f32x4  __attribute__((ext_vector_type(4)));

#define B_DIM 2
#define T_LEN 2048
#define D_DIM 1024
#define N_HEAD 16
#define HEAD_D 64
#define M_ROWS (B_DIM * T_LEN)  // 4096

// ---------------- f32 -> bf16 conversion (vectorized x4) ----------------
__global__ void cvt_f32_bf16(const float* __restrict__ src, bf16* __restrict__ dst, int n4) {
    int id = blockIdx.x * blockDim.x + threadIdx.x;
    if (id >= n4) return;
    float4 v = reinterpret_cast<const float4*>(src)[id];
    bf16x4 w;
    w[0] = (bf16)v.x; w[1] = (bf16)v.y; w[2] = (bf16)v.z; w[3] = (bf16)v.w;
    reinterpret_cast<bf16x4*>(dst)[id] = w;
}

// ---------------- GEMM: C[M,N] = A[M,K] * Bm[N,K]^T (bf16 in, f32 acc) ----
// MODE 0: write bf16 head-major [B,H,T,hd]      (q,k)
// MODE 1: write f32 row-major [M,N]             (final output)
// MODE 2: write bf16 head-major TRANSPOSED [B,H,hd,T]  (v)
template <int MODE>
__global__ __launch_bounds__(256)
void gemm_bt(const bf16* __restrict__ A, const bf16* __restrict__ Bm, void* __restrict__ Cout) {
    constexpr int K = D_DIM;
    __shared__ bf16 As[128][72];   // pad: row stride 144B (16B-aligned)
    __shared__ bf16 Bs[128][72];
    const int tid  = threadIdx.x;
    const int lane = tid & 63, wave = tid >> 6;
    const int wr = wave >> 1, wc = wave & 1;     // 2x2 waves of 64x64
    const int m0 = blockIdx.y * 128, n0 = blockIdx.x * 128;
    const int rowg = lane >> 4, col0 = lane & 15;

    f32x4 acc[4][4];
    f32x4 zero = {0.f, 0.f, 0.f, 0.f};
#pragma unroll
    for (int i = 0; i < 4; i++)
#pragma unroll
        for (int j = 0; j < 4; j++) acc[i][j] = zero;

    for (int k0 = 0; k0 < K; k0 += 64) {
#pragma unroll
        for (int cc = 0; cc < 4; ++cc) {
            int c = tid + cc * 256;            // 0..1023
            int row = c >> 3, cg = c & 7;
            *reinterpret_cast<uint4*>(&As[row][cg * 8]) =
                *reinterpret_cast<const uint4*>(A + (size_t)(m0 + row) * K + k0 + cg * 8);
            *reinterpret_cast<uint4*>(&Bs[row][cg * 8]) =
                *reinterpret_cast<const uint4*>(Bm + (size_t)(n0 + row) * K + k0 + cg * 8);
        }
        __syncthreads();
#pragma unroll
        for (int kk = 0; kk < 2; ++kk) {
            const int kc = kk * 32 + rowg * 8;
            bf16x8 af[4], bfr[4];
#pragma unroll
            for (int i = 0; i < 4; i++)
                af[i] = *reinterpret_cast<const bf16x8*>(&As[wr * 64 + i * 16 + col0][kc]);
#pragma unroll
            for (int j = 0; j < 4; j++)
                bfr[j] = *reinterpret_cast<const bf16x8*>(&Bs[wc * 64 + j * 16 + col0][kc]);
#pragma unroll
            for (int i = 0; i < 4; i++)
#pragma unroll
                for (int j = 0; j < 4; j++)
                    acc[i][j] = __builtin_amdgcn_mfma_f32_16x16x32_bf16(af[i], bfr[j], acc[i][j], 0, 0, 0);
        }
        __syncthreads();
    }

    // epilogue: C/D layout col=lane&15, row=(lane>>4)*4+r
#pragma unroll
    for (int i = 0; i < 4; i++)
#pragma unroll
        for (int j = 0; j < 4; j++) {
            if constexpr (MODE == 2) {
                bf16x4 pk;
#pragma unroll
                for (int r = 0; r < 4; r++) pk[r] = (bf16)acc[i][j][r];
                int m = m0 + wr * 64 + i * 16 + rowg * 4;
                int n = n0 + wc * 64 + j * 16 + col0;
                int b = m >> 11, t = m & 2047, h = n >> 6, d = n & 63;
                *reinterpret_cast<bf16x4*>(
                    &reinterpret_cast<bf16*>(Cout)[(((size_t)(b * N_HEAD + h)) * HEAD_D + d) * T_LEN + t]) = pk;
            } else {
#pragma unroll
                for (int r = 0; r < 4; r++) {
                    float v = acc[i][j][r];
                    int m = m0 + wr * 64 + i * 16 + rowg * 4 + r;
                    int n = n0 + wc * 64 + j * 16 + col0;
                    if constexpr (MODE == 0) {
                        int b = m >> 11, t = m & 2047, h = n >> 6, d = n & 63;
                        reinterpret_cast<bf16*>(Cout)[(((size_t)(b * N_HEAD + h)) * T_LEN + t) * HEAD_D + d] = (bf16)v;
                    } else {
                        reinterpret_cast<float*>(Cout)[(size_t)m * D_DIM + n] = v;
                    }
                }
            }
        }
}

// ---------------- RoPE in place on head-major q,k; q gets 1/8 scale -------
__global__ void rope_inplace(bf16* __restrict__ q, bf16* __restrict__ k,
                             const float* __restrict__ cosT, const float* __restrict__ sinT) {
    int id = blockIdx.x * blockDim.x + threadIdx.x;   // B*H*T*32 = 2^21 threads
    int i = id & 31;
    int t = (id >> 5) & 2047;
    int bh = id >> 16;
    float c = cosT[t * 32 + i], s = sinT[t * 32 + i];
    size_t p = ((size_t)bh * T_LEN + t) * HEAD_D + 2 * i;
    float q0 = (float)q[p], q1 = (float)q[p + 1];
    q[p]     = (bf16)((q0 * c - q1 * s) * 0.125f);
    q[p + 1] = (bf16)((q0 * s + q1 * c) * 0.125f);
    float k0 = (float)k[p], k1 = (float)k[p + 1];
    k[p]     = (bf16)(k0 * c - k1 * s);
    k[p + 1] = (bf16)(k0 * s + k1 * c);
}

// ---------------- causal flash attention -------------------------------
// 8 waves x 16 q-rows = QBLK 128; KVBLK 64; paired causal blocks (i, 15-i).
// Swapped QK^T: sT = mfma(K_frag, Q_frag) -> lane holds S^T[k][q], q = lane&15.
// K row-major [t][d] swizzled; V staged from pre-transposed global [d][t] swizzled.
__global__ __launch_bounds__(512)
void attn_fwd(const bf16* __restrict__ qh, const bf16* __restrict__ kh,
              const bf16* __restrict__ vtg, bf16* __restrict__ ao) {
    __shared__ __align__(16) bf16 Ks[2][64 * 64];
    __shared__ __align__(16) bf16 Vs[2][64 * 64];
    __shared__ __align__(16) bf16 Ps[8][16][72];
    const int tid = threadIdx.x, lane = tid & 63, w = tid >> 6;
    const int g = lane >> 4, q15 = lane & 15;
    const int pi = blockIdx.x, bh = blockIdx.y;
    const size_t kbase = (size_t)bh * T_LEN * HEAD_D;   // [t][d]
    const size_t vbase = (size_t)bh * HEAD_D * T_LEN;   // [d][t]
    // staging: 512 threads, 64 rows x 8 chunks of 16B
    const int srow = tid >> 3, scg = tid & 7;
    const int sel = srow * 64 + ((scg * 8) ^ ((srow & 7) * 8));   // swizzled elem idx
    const int ksw = (q15 & 7) * 8;                                 // read-side swizzle

    const float NEGINF = -__builtin_inff();
    f32x4 zero = {0.f, 0.f, 0.f, 0.f};

    for (int ph = 0; ph < 2; ++ph) {
        const int qi = ph ? (15 - pi) : pi;
        const int q0 = qi * 128;
        const int nt = 2 * qi + 2;
        const int qlo = q0 + w * 16;

        // Q fragments (rope'd, pre-scaled by 1/8): B-frag rows = q
        bf16x8 aq[2];
#pragma unroll
        for (int kk = 0; kk < 2; ++kk)
            aq[kk] = *reinterpret_cast<const bf16x8*>(
                &qh[kbase + (size_t)(qlo + q15) * HEAD_D + kk * 32 + g * 8]);

        f32x4 o[4];
#pragma unroll
        for (int j = 0; j < 4; j++) o[j] = zero;
        float mi = NEGINF, li = 0.f;

        // prologue: stage tile 0 into buf 0
        {
            uint4 kr = *reinterpret_cast<const uint4*>(&kh[kbase + (size_t)srow * HEAD_D + scg * 8]);
            uint4 vr = *reinterpret_cast<const uint4*>(&vtg[vbase + (size_t)srow * T_LEN + scg * 8]);
            *reinterpret_cast<uint4*>(&Ks[0][sel]) = kr;
            *reinterpret_cast<uint4*>(&Vs[0][sel]) = vr;
        }
        __syncthreads();

        for (int kt = 0; kt < nt; ++kt) {
            const int cur = kt & 1;
            const int kv0 = kt * 64;
            const bool pf = (kt + 1 < nt);
            uint4 kr, vr;
            if (pf) {   // issue next-tile global loads early (T14)
                kr = *reinterpret_cast<const uint4*>(&kh[kbase + (size_t)(kv0 + 64 + srow) * HEAD_D + scg * 8]);
                vr = *reinterpret_cast<const uint4*>(&vtg[vbase + (size_t)srow * T_LEN + kv0 + 64 + scg * 8]);
            }

            // S^T = K * Q^T : lane holds S[k = kv0+j*16+g*4+r][q = qlo+q15]
            f32x4 sT[4];
#pragma unroll
            for (int j = 0; j < 4; j++) sT[j] = zero;
#pragma unroll
            for (int kk = 0; kk < 2; ++kk) {
                const int ko = (kk * 32 + g * 8) ^ ksw;
#pragma unroll
                for (int j = 0; j < 4; j++) {
                    bf16x8 bk = *reinterpret_cast<const bf16x8*>(&Ks[cur][(j * 16 + q15) * 64 + ko]);
                    sT[j] = __builtin_amdgcn_mfma_f32_16x16x32_bf16(bk, aq[kk], sT[j], 0, 0, 0);
                }
            }
            // causal mask (uniform per wave for full tiles)
            if (kv0 + 63 > qlo) {
                const int qg = qlo + q15;
#pragma unroll
                for (int j = 0; j < 4; j++)
#pragma unroll
                    for (int r = 0; r < 4; r++)
                        if (kv0 + j * 16 + g * 4 + r > qg) sT[j][r] = NEGINF;
            }
            // online softmax: row (one q) lives in 4 lanes (groups), 16 vals each
            float mx = sT[0][0];
#pragma unroll
            for (int j = 0; j < 4; j++)
#pragma unroll
                for (int r = 0; r < 4; r++) mx = fmaxf(mx, sT[j][r]);
            mx = fmaxf(mx, __shfl_xor(mx, 16));
            mx = fmaxf(mx, __shfl_xor(mx, 32));
            const float mnew = fmaxf(mi, mx);
            const float al = __expf(mi - mnew);
            float ps = 0.f;
#pragma unroll
            for (int j = 0; j < 4; j++)
#pragma unroll
                for (int r = 0; r < 4; r++) {
                    float p = __expf(sT[j][r] - mnew);
                    sT[j][r] = p;
                    ps += p;
                }
            ps += __shfl_xor(ps, 16);
            ps += __shfl_xor(ps, 32);
            li = li * al + ps;
            mi = mnew;
            // P -> per-wave LDS (pairs, bf16)
#pragma unroll
            for (int j = 0; j < 4; j++)
#pragma unroll
                for (int pr = 0; pr < 2; ++pr) {
                    bf16x2 pk;
                    pk[0] = (bf16)sT[j][2 * pr];
                    pk[1] = (bf16)sT[j][2 * pr + 1];
                    *reinterpret_cast<bf16x2*>(&Ps[w][q15][j * 16 + g * 4 + 2 * pr]) = pk;
                }
            // rescale O (alpha lives in lane q15=q; O rows are g*4+r)
#pragma unroll
            for (int r = 0; r < 4; r++) {
                float ar = __shfl(al, g * 4 + r, 64);
#pragma unroll
                for (int j = 0; j < 4; j++) o[j][r] *= ar;
            }
            // O += P * V  (A-frag from Ps, B-frag from Vs)
#pragma unroll
            for (int kk = 0; kk < 2; ++kk) {
                bf16x8 pa = *reinterpret_cast<const bf16x8*>(&Ps[w][q15][kk * 32 + g * 8]);
                const int ko = (kk * 32 + g * 8) ^ ksw;
#pragma unroll
                for (int j = 0; j < 4; j++) {
                    bf16x8 bv = *reinterpret_cast<const bf16x8*>(&Vs[cur][(j * 16 + q15) * 64 + ko]);
                    o[j] = __builtin_amdgcn_mfma_f32_16x16x32_bf16(pa, bv, o[j], 0, 0, 0);
                }
            }
            // write next tile into the other buffer, one barrier per tile
            if (pf) {
                *reinterpret_cast<uint4*>(&Ks[cur ^ 1][sel]) = kr;
                *reinterpret_cast<uint4*>(&Vs[cur ^ 1][sel]) = vr;
            }
            __syncthreads();
        }

        // epilogue: O element (q = qlo + g*4+r, d = j*16 + q15)
        const int b = bh >> 4, h = bh & 15;
#pragma unroll
        for (int r = 0; r < 4; r++) {
            float lr = __shfl(li, g * 4 + r, 64);
            float inv = 1.f / lr;
            int t = qlo + g * 4 + r;
#pragma unroll
            for (int j = 0; j < 4; j++) {
                int d = j * 16 + q15;
                ao[((size_t)(b * T_LEN + t)) * D_DIM + h * HEAD_D + d] = (bf16)(o[j][r] * inv);
            }
        }
    }
}

// --------------------------------------------------------------------------
extern "C" void kernel_launch(void* const* d_in, const int* in_sizes, int n_in,
                              void* d_out, int out_size, void* d_ws, size_t ws_size,
                              hipStream_t stream) {
    const float* x  = (const float*)d_in[0];
    const float* Wq = (const float*)d_in[1];
    const float* Wk = (const float*)d_in[2];
    const float* Wv = (const float*)d_in[3];
    const float* Wo = (const float*)d_in[4];
    const float* fc = (const float*)d_in[5];
    const float* fs = (const float*)d_in[6];
    float* out = (float*)d_out;

    char* ws = (char*)d_ws;
    const size_t MB = 1024 * 1024;
    bf16* xb  = (bf16*)(ws);             // 8 MiB  [4096,1024]
    bf16* wqb = (bf16*)(ws + 8 * MB);
    bf16* wkb = (bf16*)(ws + 10 * MB);
    bf16* wvb = (bf16*)(ws + 12 * MB);
    bf16* wob = (bf16*)(ws + 14 * MB);
    bf16* qhd = (bf16*)(ws + 16 * MB);   // head-major [B,H,T,hd]
    bf16* khd = (bf16*)(ws + 24 * MB);
    bf16* vt  = (bf16*)(ws + 32 * MB);   // head-major transposed [B,H,hd,T]
    bf16* ao  = (bf16*)(ws + 40 * MB);   // row-major [B*T, D]

    cvt_f32_bf16<<<4096, 256, 0, stream>>>(x, xb, M_ROWS * D_DIM / 4);
    cvt_f32_bf16<<<1024, 256, 0, stream>>>(Wq, wqb, D_DIM * D_DIM / 4);
    cvt_f32_bf16<<<1024, 256, 0, stream>>>(Wk, wkb, D_DIM * D_DIM / 4);
    cvt_f32_bf16<<<1024, 256, 0, stream>>>(Wv, wvb, D_DIM * D_DIM / 4);
    cvt_f32_bf16<<<1024, 256, 0, stream>>>(Wo, wob, D_DIM * D_DIM / 4);

    dim3 gg(D_DIM / 128, M_ROWS / 128);  // (8, 32)
    gemm_bt<0><<<gg, 256, 0, stream>>>(xb, wqb, qhd);
    gemm_bt<0><<<gg, 256, 0, stream>>>(xb, wkb, khd);
    gemm_bt<2><<<gg, 256, 0, stream>>>(xb, wvb, vt);

    rope_inplace<<<(B_DIM * N_HEAD * T_LEN * 32) / 256, 256, 0, stream>>>(qhd, khd, fc, fs);

    dim3 ga(8, B_DIM * N_HEAD);          // paired causal q-tiles
    attn_fwd<<<ga, 512, 0, stream>>>(qhd, khd, vt, ao);

    gemm_bt<1><<<gg, 256, 0, stream>>>(ao, wob, out);
}

// Round 3
// 119.784 us; speedup vs baseline: 2.3046x; 1.3659x over previous
//
#include <hip/hip_runtime.h>
#include <math.h>

typedef __bf16 bf16;
typedef __bf16 bf16x8 __attribute__((ext_vector_type(8)));
typedef __bf16 bf16x4 __attribute__((ext_vector_type(4)));
typedef __bf16 bf16x2 __attribute__((ext_vector_type(2)));
typedef float  f32x4  __attribute__((ext_vector_type(4)));

#define B_DIM 2
#define T_LEN 2048
#define D_DIM 1024
#define N_HEAD 16
#define HEAD_D 64
#define M_ROWS (B_DIM * T_LEN)  // 4096

#define GLDS16(g, l)                                                          \
    __builtin_amdgcn_global_load_lds(                                         \
        (const __attribute__((address_space(1))) void*)(g),                   \
        (__attribute__((address_space(3))) void*)(l), 16, 0, 0)

// ---------------- fused f32 -> bf16 conversion of x + all weights ---------
// wqkv = concat(Wq, Wk, Wv) rows; wob separate.
__global__ void prep_cvt(const float* __restrict__ x, const float* __restrict__ wq,
                         const float* __restrict__ wk, const float* __restrict__ wv,
                         const float* __restrict__ wo, bf16* __restrict__ xb,
                         bf16* __restrict__ wqkv, bf16* __restrict__ wob) {
    int id = blockIdx.x * blockDim.x + threadIdx.x;   // float4 units
    if (id >= (1 << 21)) return;                      // 2M float4 total
    const float* src; bf16* dst; int off;
    if (id < (1 << 20)) { src = x; dst = xb; off = id; }
    else {
        int r = id - (1 << 20);
        int wi = r >> 18;                             // 0..3
        off = r & ((1 << 18) - 1);
        src = wi == 0 ? wq : wi == 1 ? wk : wi == 2 ? wv : wo;
        dst = wi < 3 ? wqkv + ((size_t)wi << 20) : wob;
    }
    float4 v = reinterpret_cast<const float4*>(src)[off];
    bf16x4 w;
    w[0] = (bf16)v.x; w[1] = (bf16)v.y; w[2] = (bf16)v.z; w[3] = (bf16)v.w;
    reinterpret_cast<bf16x4*>(dst)[off] = w;
}

// ---------------- GEMM (m97 structure): C = A[M,K] * Bm[N,K]^T ------------
// global_load_lds staging, source-side XOR swizzle, linear LDS.
// MODE 0: N=3072 fused QKV -> q,k head-major [B,H,T,hd]; v transposed [B,H,hd,T]
// MODE 1: N=1024 -> f32 row-major [M,N]
template <int MODE>
__global__ __launch_bounds__(256)
void gemm_glds(const bf16* __restrict__ A, const bf16* __restrict__ Bm,
               bf16* __restrict__ q, bf16* __restrict__ k, bf16* __restrict__ v,
               float* __restrict__ outf) {
    constexpr int K = D_DIM;
    __shared__ bf16 As[128 * 64];
    __shared__ bf16 Bs[128 * 64];
    const int tid = threadIdx.x, lane = tid & 63, wave = tid >> 6;
    const int wr = wave >> 1, wc = wave & 1;
    const int rowg = lane >> 4, col0 = lane & 15;

    // XCD-aware bijective remap (nwg % 8 == 0 in both modes)
    const int nwg = gridDim.x * gridDim.y, cpx = nwg >> 3;
    const int lin = blockIdx.x + blockIdx.y * gridDim.x;
    const int nid = (lin & 7) * cpx + (lin >> 3);
    const int bx = nid % gridDim.x, by = nid / gridDim.x;
    const int m0 = by * 128, n0 = bx * 128;

    // staging: lane -> row (srow within 8-row group), fetched content chunk
    const int srow = lane >> 3;
    const int schk = (lane & 7) ^ srow;               // XOR-swizzled source chunk
    const bf16* gA = A + (size_t)(m0 + wave * 32 + srow) * K + schk * 8;
    const bf16* gB = Bm + (size_t)(n0 + wave * 32 + srow) * K + schk * 8;

    f32x4 acc[4][4];
    f32x4 zero = {0.f, 0.f, 0.f, 0.f};
#pragma unroll
    for (int i = 0; i < 4; i++)
#pragma unroll
        for (int j = 0; j < 4; j++) acc[i][j] = zero;

    for (int k0 = 0; k0 < K; k0 += 64) {
#pragma unroll
        for (int t = 0; t < 4; ++t) {
            GLDS16(gA + k0 + t * 8 * K, &As[(wave * 32 + t * 8) * 64]);
            GLDS16(gB + k0 + t * 8 * K, &Bs[(wave * 32 + t * 8) * 64]);
        }
        __syncthreads();
#pragma unroll
        for (int kk = 0; kk < 2; ++kk) {
            bf16x8 af[4], bfr[4];
#pragma unroll
            for (int i = 0; i < 4; i++) {
                int R = wr * 64 + i * 16 + col0;
                af[i] = *reinterpret_cast<const bf16x8*>(&As[R * 64 + (((kk * 4 + rowg) ^ (R & 7)) * 8)]);
            }
#pragma unroll
            for (int j = 0; j < 4; j++) {
                int R = wc * 64 + j * 16 + col0;
                bfr[j] = *reinterpret_cast<const bf16x8*>(&Bs[R * 64 + (((kk * 4 + rowg) ^ (R & 7)) * 8)]);
            }
#pragma unroll
            for (int i = 0; i < 4; i++)
#pragma unroll
                for (int j = 0; j < 4; j++)
                    acc[i][j] = __builtin_amdgcn_mfma_f32_16x16x32_bf16(af[i], bfr[j], acc[i][j], 0, 0, 0);
        }
        __syncthreads();
    }

    if constexpr (MODE == 0) {
        const int which = bx >> 3;                    // 0=q, 1=k, 2=v
        if (which < 2) {
            bf16* dst = which == 0 ? q : k;
#pragma unroll
            for (int i = 0; i < 4; i++)
#pragma unroll
                for (int j = 0; j < 4; j++)
#pragma unroll
                    for (int r = 0; r < 4; r++) {
                        int m = m0 + wr * 64 + i * 16 + rowg * 4 + r;
                        int n = (n0 + wc * 64 + j * 16 + col0) & 1023;
                        int b = m >> 11, t = m & 2047, h = n >> 6, d = n & 63;
                        dst[(((size_t)(b * N_HEAD + h)) * T_LEN + t) * HEAD_D + d] = (bf16)acc[i][j][r];
                    }
        } else {
#pragma unroll
            for (int i = 0; i < 4; i++)
#pragma unroll
                for (int j = 0; j < 4; j++) {
                    bf16x4 pk;
#pragma unroll
                    for (int r = 0; r < 4; r++) pk[r] = (bf16)acc[i][j][r];
                    int m = m0 + wr * 64 + i * 16 + rowg * 4;
                    int n = (n0 + wc * 64 + j * 16 + col0) & 1023;
                    int b = m >> 11, t = m & 2047, h = n >> 6, d = n & 63;
                    *reinterpret_cast<bf16x4*>(
                        &v[(((size_t)(b * N_HEAD + h)) * HEAD_D + d) * T_LEN + t]) = pk;
                }
        }
    } else {
#pragma unroll
        for (int i = 0; i < 4; i++)
#pragma unroll
            for (int j = 0; j < 4; j++)
#pragma unroll
                for (int r = 0; r < 4; r++) {
                    int m = m0 + wr * 64 + i * 16 + rowg * 4 + r;
                    int n = n0 + wc * 64 + j * 16 + col0;
                    outf[(size_t)m * D_DIM + n] = acc[i][j][r];
                }
    }
}

// ---------------- RoPE in place on head-major q,k; q gets 1/8 scale -------
__global__ void rope_inplace(bf16* __restrict__ q, bf16* __restrict__ k,
                             const float* __restrict__ cosT, const float* __restrict__ sinT) {
    int id = blockIdx.x * blockDim.x + threadIdx.x;   // B*H*T*32 = 2^21 threads
    int i = id & 31;
    int t = (id >> 5) & 2047;
    int bh = id >> 16;
    float c = cosT[t * 32 + i], s = sinT[t * 32 + i];
    size_t p = ((size_t)bh * T_LEN + t) * HEAD_D + 2 * i;
    float q0 = (float)q[p], q1 = (float)q[p + 1];
    q[p]     = (bf16)((q0 * c - q1 * s) * 0.125f);
    q[p + 1] = (bf16)((q0 * s + q1 * c) * 0.125f);
    float k0 = (float)k[p], k1 = (float)k[p + 1];
    k[p]     = (bf16)(k0 * c - k1 * s);
    k[p + 1] = (bf16)(k0 * s + k1 * c);
}

// ---------------- causal flash attention -------------------------------
// 8 waves x 16 q-rows = QBLK 128; KVBLK 64; paired causal q-tiles (i, 15-i).
// Swapped QK^T AND swapped PV: O^T = mfma(V_frag, P_frag) so q = lane&15
// for S, alpha/li, and O alike -> no cross-lane broadcasts on critical path.
__global__ __launch_bounds__(512)
void attn_fwd(const bf16* __restrict__ qh, const bf16* __restrict__ kh,
              const bf16* __restrict__ vtg, bf16* __restrict__ ao) {
    __shared__ __align__(16) bf16 Ks[2][64 * 64];
    __shared__ __align__(16) bf16 Vs[2][64 * 64];
    __shared__ __align__(16) bf16 Ps[8][16][72];
    const int tid = threadIdx.x, lane = tid & 63, w = tid >> 6;
    const int g = lane >> 4, q15 = lane & 15;
    // XCD remap: each XCD gets 4 complete bh (K/V panels stay in its L2)
    const int lin = blockIdx.x + blockIdx.y * 8;      // nwg = 256
    const int nid = (lin & 7) * 32 + (lin >> 3);
    const int pi = nid & 7, bh = nid >> 3;
    const size_t kbase = (size_t)bh * T_LEN * HEAD_D;   // [t][d]
    const size_t vbase = (size_t)bh * HEAD_D * T_LEN;   // [d][t]
    const int srow = tid >> 3, scg = tid & 7;
    const int sel = srow * 64 + ((scg * 8) ^ ((srow & 7) * 8));
    const int ksw = (q15 & 7) * 8;

    const float NEGINF = -__builtin_inff();
    f32x4 zero = {0.f, 0.f, 0.f, 0.f};

    for (int ph = 0; ph < 2; ++ph) {
        const int qi = ph ? (15 - pi) : pi;
        const int q0 = qi * 128;
        const int nt = 2 * qi + 2;
        const int qlo = q0 + w * 16;

        bf16x8 aq[2];
#pragma unroll
        for (int kk = 0; kk < 2; ++kk)
            aq[kk] = *reinterpret_cast<const bf16x8*>(
                &qh[kbase + (size_t)(qlo + q15) * HEAD_D + kk * 32 + g * 8]);

        f32x4 o[4];
#pragma unroll
        for (int j = 0; j < 4; j++) o[j] = zero;
        float mi = NEGINF, li = 0.f;

        {   // prologue: stage tile 0 into buf 0
            uint4 kr = *reinterpret_cast<const uint4*>(&kh[kbase + (size_t)srow * HEAD_D + scg * 8]);
            uint4 vr = *reinterpret_cast<const uint4*>(&vtg[vbase + (size_t)srow * T_LEN + scg * 8]);
            *reinterpret_cast<uint4*>(&Ks[0][sel]) = kr;
            *reinterpret_cast<uint4*>(&Vs[0][sel]) = vr;
        }
        __syncthreads();

        for (int kt = 0; kt < nt; ++kt) {
            const int cur = kt & 1;
            const int kv0 = kt * 64;
            const bool pf = (kt + 1 < nt);
            uint4 kr, vr;
            if (pf) {   // issue next-tile global loads early (T14)
                kr = *reinterpret_cast<const uint4*>(&kh[kbase + (size_t)(kv0 + 64 + srow) * HEAD_D + scg * 8]);
                vr = *reinterpret_cast<const uint4*>(&vtg[vbase + (size_t)srow * T_LEN + kv0 + 64 + scg * 8]);
            }

            // S^T: lane holds S[k = kv0+j*16+g*4+r][q = qlo+q15]
            f32x4 sT[4];
#pragma unroll
            for (int j = 0; j < 4; j++) sT[j] = zero;
            __builtin_amdgcn_s_setprio(1);
#pragma unroll
            for (int kk = 0; kk < 2; ++kk) {
                const int ko = (kk * 32 + g * 8) ^ ksw;
#pragma unroll
                for (int j = 0; j < 4; j++) {
                    bf16x8 bk = *reinterpret_cast<const bf16x8*>(&Ks[cur][(j * 16 + q15) * 64 + ko]);
                    sT[j] = __builtin_amdgcn_mfma_f32_16x16x32_bf16(bk, aq[kk], sT[j], 0, 0, 0);
                }
            }
            __builtin_amdgcn_s_setprio(0);
            if (kv0 + 63 > qlo) {
                const int qg = qlo + q15;
#pragma unroll
                for (int j = 0; j < 4; j++)
#pragma unroll
                    for (int r = 0; r < 4; r++)
                        if (kv0 + j * 16 + g * 4 + r > qg) sT[j][r] = NEGINF;
            }
            // online softmax: row of q lives in 4 lanes (g-groups), 16 vals each
            float mx = sT[0][0];
#pragma unroll
            for (int j = 0; j < 4; j++)
#pragma unroll
                for (int r = 0; r < 4; r++) mx = fmaxf(mx, sT[j][r]);
            mx = fmaxf(mx, __shfl_xor(mx, 16));
            mx = fmaxf(mx, __shfl_xor(mx, 32));
            const float mnew = fmaxf(mi, mx);
            const float al = __expf(mi - mnew);
            float ps = 0.f;
#pragma unroll
            for (int j = 0; j < 4; j++)
#pragma unroll
                for (int r = 0; r < 4; r++) {
                    float p = __expf(sT[j][r] - mnew);
                    sT[j][r] = p;
                    ps += p;
                }
            ps += __shfl_xor(ps, 16);
            ps += __shfl_xor(ps, 32);
            li = li * al + ps;
            mi = mnew;
            // P -> per-wave LDS (B-frag layout source)
#pragma unroll
            for (int j = 0; j < 4; j++)
#pragma unroll
                for (int pr = 0; pr < 2; ++pr) {
                    bf16x2 pk;
                    pk[0] = (bf16)sT[j][2 * pr];
                    pk[1] = (bf16)sT[j][2 * pr + 1];
                    *reinterpret_cast<bf16x2*>(&Ps[w][q15][j * 16 + g * 4 + 2 * pr]) = pk;
                }
            // rescale O: q = lane&15 for O too -> own-lane alpha
#pragma unroll
            for (int j = 0; j < 4; j++)
#pragma unroll
                for (int r = 0; r < 4; r++) o[j][r] *= al;
            // O^T += V^T * P^T  (A = V fragment, B = P fragment)
            __builtin_amdgcn_s_setprio(1);
#pragma unroll
            for (int kk = 0; kk < 2; ++kk) {
                bf16x8 pb = *reinterpret_cast<const bf16x8*>(&Ps[w][q15][kk * 32 + g * 8]);
                const int ko = (kk * 32 + g * 8) ^ ksw;
#pragma unroll
                for (int j = 0; j < 4; j++) {
                    bf16x8 av = *reinterpret_cast<const bf16x8*>(&Vs[cur][(j * 16 + q15) * 64 + ko]);
                    o[j] = __builtin_amdgcn_mfma_f32_16x16x32_bf16(av, pb, o[j], 0, 0, 0);
                }
            }
            __builtin_amdgcn_s_setprio(0);
            if (pf) {
                *reinterpret_cast<uint4*>(&Ks[cur ^ 1][sel]) = kr;
                *reinterpret_cast<uint4*>(&Vs[cur ^ 1][sel]) = vr;
            }
            __syncthreads();
        }

        // epilogue: lane owns q = qlo + q15, d = j*16 + g*4 + r
        const int b = bh >> 4, h = bh & 15;
        const float inv = 1.f / li;
        const int t = qlo + q15;
        bf16* dst = &ao[((size_t)(b * T_LEN + t)) * D_DIM + h * HEAD_D];
#pragma unroll
        for (int j = 0; j < 4; j++) {
            bf16x4 pk;
#pragma unroll
            for (int r = 0; r < 4; r++) pk[r] = (bf16)(o[j][r] * inv);
            *reinterpret_cast<bf16x4*>(&dst[j * 16 + g * 4]) = pk;
        }
    }
}

// --------------------------------------------------------------------------
extern "C" void kernel_launch(void* const* d_in, const int* in_sizes, int n_in,
                              void* d_out, int out_size, void* d_ws, size_t ws_size,
                              hipStream_t stream) {
    const float* x  = (const float*)d_in[0];
    const float* Wq = (const float*)d_in[1];
    const float* Wk = (const float*)d_in[2];
    const float* Wv = (const float*)d_in[3];
    const float* Wo = (const float*)d_in[4];
    const float* fc = (const float*)d_in[5];
    const float* fs = (const float*)d_in[6];
    float* out = (float*)d_out;

    char* ws = (char*)d_ws;
    const size_t MB = 1024 * 1024;
    bf16* xb   = (bf16*)(ws);             // 8 MiB  [4096,1024]
    bf16* wqkv = (bf16*)(ws + 8 * MB);    // 6 MiB  [3072,1024]
    bf16* wob  = (bf16*)(ws + 14 * MB);   // 2 MiB
    bf16* qhd  = (bf16*)(ws + 16 * MB);   // head-major [B,H,T,hd]
    bf16* khd  = (bf16*)(ws + 24 * MB);
    bf16* vt   = (bf16*)(ws + 32 * MB);   // head-major transposed [B,H,hd,T]
    bf16* ao   = (bf16*)(ws + 40 * MB);   // row-major [B*T, D]

    prep_cvt<<<8192, 256, 0, stream>>>(x, Wq, Wk, Wv, Wo, xb, wqkv, wob);

    dim3 gq(24, 32);   // fused QKV: N = 3072
    gemm_glds<0><<<gq, 256, 0, stream>>>(xb, wqkv, qhd, khd, vt, nullptr);

    rope_inplace<<<(B_DIM * N_HEAD * T_LEN * 32) / 256, 256, 0, stream>>>(qhd, khd, fc, fs);

    dim3 ga(8, B_DIM * N_HEAD);           // paired causal q-tiles
    attn_fwd<<<ga, 512, 0, stream>>>(qhd, khd, vt, ao);

    dim3 go(8, 32);
    gemm_glds<1><<<go, 256, 0, stream>>>(ao, wob, nullptr, nullptr, nullptr, out);
}